// Round 7
// baseline (613.182 us; speedup 1.0000x reference)
//
#include <hip/hip_runtime.h>
#include <math.h>

#define T_STEPS 1000
#define BATCH   256
#define IN_DIM  3
#define HID     512
#define OUT_DIM 2
#define BETA    0.8f
#define THRESH  1.0f
#define TAIL    10

typedef float f32x4 __attribute__((ext_vector_type(4)));

// Phase A: T=1000 LIF recurrence -> PACKED SPIKE BITS in d_ws (16.4 MB).
// Block = 512 threads = one batch row b (one h per thread, 8 waves).
// Each wave ballots its 64 spike predicates into a uint64 per t; lane 0
// stores it. Word layout matches output order: word g/64 for float g.
// Store traffic is only 16 MB -> kernel is VALU-bound (~25 us), freeing the
// 524 MB stream for a fill-shaped kernel.
__global__ __launch_bounds__(512) void snn_spikes(const float* __restrict__ x,
                                                  const float* __restrict__ W1,
                                                  unsigned long long* __restrict__ bits) {
    __shared__ float xs[T_STEPS * IN_DIM];  // 12 KB: x[:, b, :]
    const int b  = blockIdx.x;
    const int h  = threadIdx.x;             // 0..511
    const int wv = h >> 6;                  // wave id 0..7

    for (int k = threadIdx.x; k < T_STEPS * IN_DIM; k += 512) {
        int t = k / 3, i = k - 3 * t;
        xs[k] = x[t * (BATCH * IN_DIM) + b * IN_DIM + i];
    }
    const float w0 = W1[h * 3 + 0];
    const float w1 = W1[h * 3 + 1];
    const float w2 = W1[h * 3 + 2];
    __syncthreads();

    float mem = 0.0f;
    // word index for (t,b,h0=wv*64): t*2048 + b*8 + wv
    unsigned long long* wp = bits + (size_t)b * 8 + wv;
    #pragma unroll 2
    for (int t = 0; t < T_STEPS; ++t) {
        const float cur = fmaf(xs[3 * t + 0], w0,
                          fmaf(xs[3 * t + 1], w1, xs[3 * t + 2] * w2));
        // snntorch Leaky, reset='zero': reset uses PREVIOUS mem
        const float keep = (mem > THRESH) ? 0.0f : 1.0f;
        mem = fmaf(BETA, mem, cur) * keep;
        const unsigned long long m = __ballot(mem > THRESH);
        if ((h & 63) == 0) wp[(size_t)t * (BATCH * HID / 64)] = m;
    }
}

// Phase B: bit -> float expansion, structured EXACTLY like the 6.2 TB/s fill:
// 2048 blocks x 256 threads (max occupancy, tiny VGPR), each block sweeps
// 16-KB regions grid-stride; per region each wave issues 4 back-to-back
// contiguous 1-KB dwordx4 stores. Reads 16 MB (L2-resident), writes 524 MB.
__global__ __launch_bounds__(256) void snn_expand(const unsigned long long* __restrict__ bits,
                                                  float* __restrict__ spk) {
    const int NREG = T_STEPS * BATCH * HID / 4096;  // 32000 regions of 4096 floats
    const int T   = threadIdx.x;
    const int sub = T & 15;        // nibble index within word
    const int wrd = T >> 4;        // word index within round

    for (int reg = blockIdx.x; reg < NREG; reg += gridDim.x) {
        const unsigned long long* wb = bits + (size_t)reg * 64;
        float* op = spk + (size_t)reg * 4096;
        #pragma unroll
        for (int r = 0; r < 4; ++r) {
            // float f = reg*4096 + r*1024 + T*4 + i  ->  word f/64, bit f%64
            const unsigned long long m = wb[r * 16 + wrd];
            const unsigned nib = (unsigned)(m >> (sub * 4)) & 0xFu;
            f32x4 v;
            v.x = (nib & 1u) ? 1.0f : 0.0f;
            v.y = (nib & 2u) ? 1.0f : 0.0f;
            v.z = (nib & 4u) ? 1.0f : 0.0f;
            v.w = (nib & 8u) ? 1.0f : 0.0f;
            *(f32x4*)(op + r * 1024 + T * 4) = v;
        }
    }
}

// avg_out[b][o] = mean over last 10 t of sigmoid( sum_h spk[t,b,h] * W2[o,h] )
// One block per b; 10 waves, one per tail timestep; LDS combine.
__global__ __launch_bounds__(640) void snn_tail(const float* __restrict__ spk,
                                                const float* __restrict__ W2,
                                                float* __restrict__ avg) {
    __shared__ float partial[TAIL][OUT_DIM];
    const int b    = blockIdx.x;
    const int wv   = threadIdx.x >> 6;   // 0..9 = tail index
    const int lane = threadIdx.x & 63;
    const int t    = T_STEPS - TAIL + wv;

    const float* sp = spk + (size_t)t * (BATCH * HID) + b * HID;
    float s0 = 0.0f, s1 = 0.0f;
    #pragma unroll
    for (int j = 0; j < 8; ++j) {
        const int h = lane + j * 64;
        const float v = sp[h];
        s0 = fmaf(v, W2[h], s0);
        s1 = fmaf(v, W2[HID + h], s1);
    }
    #pragma unroll
    for (int off = 32; off > 0; off >>= 1) {
        s0 += __shfl_down(s0, off, 64);
        s1 += __shfl_down(s1, off, 64);
    }
    if (lane == 0) {
        partial[wv][0] = 1.0f / (1.0f + expf(-s0));
        partial[wv][1] = 1.0f / (1.0f + expf(-s1));
    }
    __syncthreads();
    if (threadIdx.x < OUT_DIM) {
        float a = 0.0f;
        #pragma unroll
        for (int i = 0; i < TAIL; ++i) a += partial[i][threadIdx.x];
        avg[b * OUT_DIM + threadIdx.x] = a * (1.0f / TAIL);
    }
}

extern "C" void kernel_launch(void* const* d_in, const int* in_sizes, int n_in,
                              void* d_out, int out_size, void* d_ws, size_t ws_size,
                              hipStream_t stream) {
    const float* x  = (const float*)d_in[0];   // [1000,256,3]
    const float* W1 = (const float*)d_in[1];   // [512,3]
    const float* W2 = (const float*)d_in[2];   // [2,512]
    float* out = (float*)d_out;
    float* spk = out;                                        // [1000,256,512]
    float* avg = out + (size_t)T_STEPS * BATCH * HID;        // [256,2]
    unsigned long long* bits = (unsigned long long*)d_ws;    // 16.4 MB of d_ws

    snn_spikes<<<dim3(BATCH), dim3(512), 0, stream>>>(x, W1, bits);
    snn_expand<<<dim3(2048), dim3(256), 0, stream>>>(bits, spk);
    snn_tail  <<<dim3(BATCH), dim3(640), 0, stream>>>(spk, W2, avg);
}

// Round 8
// 503.613 us; speedup vs baseline: 1.2176x; 1.2176x over previous
//
#include <hip/hip_runtime.h>
#include <math.h>

#define T_STEPS 1000
#define BATCH   256
#define IN_DIM  3
#define HID     512
#define OUT_DIM 2
#define BETA    0.8f
#define THRESH  1.0f
#define TAIL    10

typedef float f32x4 __attribute__((ext_vector_type(4)));

// Best-measured variant (R4, 504.9 us total). Accounting post-mortem (R7):
// ~425 us of dur_us is the harness's own d_ws (2 GB) + d_out (524 MB) poison
// fills inside the timed region; this kernel's controllable part is ~80 us =
// 524 MB at ~6.5 TB/s -> at the HBM write roofline (fill kernel = 6.2 TB/s).
//
// Block = 256 threads (4 waves) covering 2 adjacent batch rows; per t the
// block writes 4 KB contiguous; grid = 128 blocks progressing uniformly ->
// device-wide ~512 KB contiguous sweeping write band. __syncthreads every
// 4 t keeps the block's waves time-clustered.
__global__ __launch_bounds__(256) void snn_main(const float* __restrict__ x,
                                                const float* __restrict__ W1,
                                                float* __restrict__ spk) {
    __shared__ float xs[2][T_STEPS * IN_DIM + 8];  // ~24 KB: x[:, b0, :], x[:, b0+1, :]
    const int bp   = blockIdx.x;            // b-pair index, b = 2*bp + boff
    const int flat = (int)threadIdx.x * 4;  // 0..1023 across 2 rows
    const int boff = flat >> 9;             // 0 or 1
    const int h0   = flat & 511;

    for (int k = threadIdx.x; k < 2 * T_STEPS * IN_DIM; k += 256) {
        int bb = k >= T_STEPS * IN_DIM;
        int kk = k - bb * T_STEPS * IN_DIM;
        int t = kk / 3, i = kk - 3 * t;
        xs[bb][kk] = x[t * (BATCH * IN_DIM) + (2 * bp + bb) * IN_DIM + i];
    }
    float w[4][3];
    #pragma unroll
    for (int j = 0; j < 4; ++j)
        #pragma unroll
        for (int i = 0; i < 3; ++i)
            w[j][i] = W1[(h0 + j) * 3 + i];
    __syncthreads();

    const float* xrow = xs[boff];
    float mem[4] = {0.0f, 0.0f, 0.0f, 0.0f};
    f32x4* op = (f32x4*)(spk + (size_t)(2 * bp) * HID + flat);

    for (int t4 = 0; t4 < T_STEPS; t4 += 4) {
        #pragma unroll
        for (int u = 0; u < 4; ++u) {
            const int t = t4 + u;
            const float x0 = xrow[t * 3 + 0];
            const float x1 = xrow[t * 3 + 1];
            const float x2 = xrow[t * 3 + 2];
            f32x4 s;
            #pragma unroll
            for (int j = 0; j < 4; ++j) {
                const float cur = fmaf(x0, w[j][0], fmaf(x1, w[j][1], x2 * w[j][2]));
                // snntorch Leaky, reset='zero': reset uses PREVIOUS mem
                const float keep = (mem[j] > THRESH) ? 0.0f : 1.0f;
                mem[j] = fmaf(BETA, mem[j], cur) * keep;
                s[j] = (mem[j] > THRESH) ? 1.0f : 0.0f;
            }
            __builtin_nontemporal_store(s, op + (size_t)t * (BATCH * HID / 4));
        }
        __syncthreads();  // keep the 4 waves' store streams time-clustered
    }
}

// avg_out[b][o] = mean over last 10 t of sigmoid( sum_h spk[t,b,h] * W2[o,h] )
// One block per b; 10 waves, one per tail timestep; LDS combine.
__global__ __launch_bounds__(640) void snn_tail(const float* __restrict__ spk,
                                                const float* __restrict__ W2,
                                                float* __restrict__ avg) {
    __shared__ float partial[TAIL][OUT_DIM];
    const int b    = blockIdx.x;
    const int wv   = threadIdx.x >> 6;   // 0..9 = tail index
    const int lane = threadIdx.x & 63;
    const int t    = T_STEPS - TAIL + wv;

    const float* sp = spk + (size_t)t * (BATCH * HID) + b * HID;
    float s0 = 0.0f, s1 = 0.0f;
    #pragma unroll
    for (int j = 0; j < 8; ++j) {
        const int h = lane + j * 64;
        const float v = sp[h];
        s0 = fmaf(v, W2[h], s0);
        s1 = fmaf(v, W2[HID + h], s1);
    }
    #pragma unroll
    for (int off = 32; off > 0; off >>= 1) {
        s0 += __shfl_down(s0, off, 64);
        s1 += __shfl_down(s1, off, 64);
    }
    if (lane == 0) {
        partial[wv][0] = 1.0f / (1.0f + expf(-s0));
        partial[wv][1] = 1.0f / (1.0f + expf(-s1));
    }
    __syncthreads();
    if (threadIdx.x < OUT_DIM) {
        float a = 0.0f;
        #pragma unroll
        for (int i = 0; i < TAIL; ++i) a += partial[i][threadIdx.x];
        avg[b * OUT_DIM + threadIdx.x] = a * (1.0f / TAIL);
    }
}

extern "C" void kernel_launch(void* const* d_in, const int* in_sizes, int n_in,
                              void* d_out, int out_size, void* d_ws, size_t ws_size,
                              hipStream_t stream) {
    const float* x  = (const float*)d_in[0];   // [1000,256,3]
    const float* W1 = (const float*)d_in[1];   // [512,3]
    const float* W2 = (const float*)d_in[2];   // [2,512]
    float* out = (float*)d_out;
    float* spk = out;                                        // [1000,256,512]
    float* avg = out + (size_t)T_STEPS * BATCH * HID;        // [256,2]

    snn_main<<<dim3(BATCH / 2), dim3(256), 0, stream>>>(x, W1, spk);
    snn_tail<<<dim3(BATCH), dim3(640), 0, stream>>>(spk, W2, avg);
}